// Round 1
// baseline (790.022 us; speedup 1.0000x reference)
//
#include <hip/hip_runtime.h>
#include <hip/hip_bf16.h>

#define B_ 2
#define S_ 2048
#define HID_ 1024
#define NH_ 16
#define HD_ 64
#define MTOK (B_*S_)

typedef __attribute__((ext_vector_type(8))) __bf16 bf16x8;
typedef __attribute__((ext_vector_type(4))) __bf16 bf16x4;
typedef __attribute__((ext_vector_type(4))) float f32x4;

// ---------------- f32 -> bf16 cast (vectorized x4) ----------------
__global__ __launch_bounds__(256) void cast_bf16_kernel(
    const float* __restrict__ in, __bf16* __restrict__ out, int n4)
{
  int i = blockIdx.x * 256 + threadIdx.x;
  if (i >= n4) return;
  float4 v = reinterpret_cast<const float4*>(in)[i];
  bf16x4 o;
  o[0] = (__bf16)v.x; o[1] = (__bf16)v.y; o[2] = (__bf16)v.z; o[3] = (__bf16)v.w;
  reinterpret_cast<bf16x4*>(out)[i] = o;
}

// ---------------- C = A @ W^T + bias, optional per-row scale -------
// A: M x K bf16 row-major, W: N x K bf16 row-major. 128x128 tile, 4 waves.
template<bool F32OUT>
__global__ __launch_bounds__(256) void gemm_bt(
    const __bf16* __restrict__ A, const __bf16* __restrict__ W,
    const float* __restrict__ bias, const float* __restrict__ rowscale,
    void* __restrict__ Cout, int M, int N, int K)
{
  __shared__ __bf16 As[128][40];   // pitch 40 shorts (80B) -> 2-way banks (free)
  __shared__ __bf16 Bs[128][40];
  const int t = threadIdx.x;
  const int m0 = blockIdx.y * 128;
  const int n0 = blockIdx.x * 128;
  const int lr = t >> 1;
  const int lc = (t & 1) * 16;
  const int lane = t & 63;
  const int wave = t >> 6;
  const int wr = (wave >> 1) * 64;
  const int wc = (wave & 1) * 64;
  const int fr = lane & 15;
  const int kg = lane >> 4;

  f32x4 acc[4][4];
  #pragma unroll
  for (int i = 0; i < 4; i++)
    #pragma unroll
    for (int j = 0; j < 4; j++) acc[i][j] = (f32x4)0.f;

  const __bf16* ap = A + (size_t)(m0 + lr) * K + lc;
  const __bf16* wp = W + (size_t)(n0 + lr) * K + lc;

  for (int k0 = 0; k0 < K; k0 += 32) {
    __syncthreads();
    *(bf16x8*)&As[lr][lc]     = *(const bf16x8*)(ap + k0);
    *(bf16x8*)&As[lr][lc + 8] = *(const bf16x8*)(ap + k0 + 8);
    *(bf16x8*)&Bs[lr][lc]     = *(const bf16x8*)(wp + k0);
    *(bf16x8*)&Bs[lr][lc + 8] = *(const bf16x8*)(wp + k0 + 8);
    __syncthreads();
    bf16x8 af[4], bf[4];
    #pragma unroll
    for (int m = 0; m < 4; m++) af[m] = *(const bf16x8*)&As[wr + m*16 + fr][kg*8];
    #pragma unroll
    for (int n = 0; n < 4; n++) bf[n] = *(const bf16x8*)&Bs[wc + n*16 + fr][kg*8];
    #pragma unroll
    for (int m = 0; m < 4; m++)
      #pragma unroll
      for (int n = 0; n < 4; n++)
        acc[m][n] = __builtin_amdgcn_mfma_f32_16x16x32_bf16(af[m], bf[n], acc[m][n], 0, 0, 0);
  }

  #pragma unroll
  for (int m = 0; m < 4; m++) {
    #pragma unroll
    for (int r = 0; r < 4; r++) {
      int row = m0 + wr + m*16 + kg*4 + r;
      float rs = rowscale ? rowscale[row] : 1.f;
      #pragma unroll
      for (int n = 0; n < 4; n++) {
        int col = n0 + wc + n*16 + fr;
        float v = (acc[m][n][r] + bias[col]) * rs;
        if (F32OUT) ((float*)Cout)[(size_t)row * N + col] = v;
        else        ((__bf16*)Cout)[(size_t)row * N + col] = (__bf16)v;
      }
    }
  }
}

// ---------------- causal flash attention, f32 VALU -----------------
// grid (S/64, B*NH), 256 threads. Thread owns q rows {tq+i*16}, and
// key cols / d cols {tk+j*16}  (strided -> conflict-free LDS reads).
__global__ __launch_bounds__(256) void flash_attn(
    const __bf16* __restrict__ Q, const __bf16* __restrict__ K,
    const __bf16* __restrict__ V, const float* __restrict__ mask,
    __bf16* __restrict__ O)
{
  __shared__ float Qs[64][68];
  __shared__ float Ks[64][68];
  __shared__ float Vs[64][68];
  __shared__ float Ps[64][68];
  __shared__ float mk[64];

  const int qt = blockIdx.x;
  const int bh = blockIdx.y;
  const int b = bh >> 4, h = bh & 15;
  const int t = threadIdx.x;
  const int tq = t >> 4;   // 0..15
  const int tk = t & 15;   // 0..15
  const float NEG = -__builtin_inff();

  {   // stage Q tile (64x64) as f32
    int r = t >> 2;
    int c0 = (t & 3) * 16;
    const __bf16* src = Q + ((size_t)(b * S_) + qt*64 + r) * HID_ + h*HD_ + c0;
    bf16x8 v0 = *(const bf16x8*)src;
    bf16x8 v1 = *(const bf16x8*)(src + 8);
    #pragma unroll
    for (int j = 0; j < 8; j++) { Qs[r][c0 + j] = (float)v0[j]; Qs[r][c0 + 8 + j] = (float)v1[j]; }
  }

  float m_i[4], l_i[4], o_[4][4];
  #pragma unroll
  for (int i = 0; i < 4; i++) {
    m_i[i] = NEG; l_i[i] = 0.f;
    #pragma unroll
    for (int j = 0; j < 4; j++) o_[i][j] = 0.f;
  }

  for (int kt = 0; kt <= qt; ++kt) {
    __syncthreads();   // protect K/V/P reuse from previous iteration
    {   // stage K, V tiles + mask
      int r = t >> 2;
      int c0 = (t & 3) * 16;
      const __bf16* ks = K + ((size_t)(b * S_) + kt*64 + r) * HID_ + h*HD_ + c0;
      const __bf16* vs = V + ((size_t)(b * S_) + kt*64 + r) * HID_ + h*HD_ + c0;
      bf16x8 k0v = *(const bf16x8*)ks;
      bf16x8 k1v = *(const bf16x8*)(ks + 8);
      bf16x8 v0v = *(const bf16x8*)vs;
      bf16x8 v1v = *(const bf16x8*)(vs + 8);
      #pragma unroll
      for (int j = 0; j < 8; j++) {
        Ks[r][c0 + j] = (float)k0v[j]; Ks[r][c0 + 8 + j] = (float)k1v[j];
        Vs[r][c0 + j] = (float)v0v[j]; Vs[r][c0 + 8 + j] = (float)v1v[j];
      }
      if (t < 64) mk[t] = mask[(size_t)b * S_ + kt*64 + t];
    }
    __syncthreads();

    // ---- QK^T: 4x4 scores per thread ----
    float s[4][4];
    #pragma unroll
    for (int i = 0; i < 4; i++)
      #pragma unroll
      for (int j = 0; j < 4; j++) s[i][j] = 0.f;
    for (int d = 0; d < 64; d += 4) {
      float4 qv[4], kv[4];
      #pragma unroll
      for (int i = 0; i < 4; i++) qv[i] = *(const float4*)&Qs[tq + i*16][d];
      #pragma unroll
      for (int j = 0; j < 4; j++) kv[j] = *(const float4*)&Ks[tk + j*16][d];
      #pragma unroll
      for (int i = 0; i < 4; i++)
        #pragma unroll
        for (int j = 0; j < 4; j++)
          s[i][j] += qv[i].x*kv[j].x + qv[i].y*kv[j].y + qv[i].z*kv[j].z + qv[i].w*kv[j].w;
    }

    // ---- online softmax (row group = 16 lanes sharing tq) ----
    #pragma unroll
    for (int i = 0; i < 4; i++) {
      int qg = qt*64 + tq + i*16;
      float tm = NEG;
      #pragma unroll
      for (int j = 0; j < 4; j++) {
        int kcol = kt*64 + tk + j*16;
        float sv = s[i][j] * 0.125f;                 // 1/sqrt(64), T=1
        bool ok = (kcol <= qg) && (mk[tk + j*16] != 0.f);
        sv = ok ? sv : NEG;
        s[i][j] = sv;
        tm = fmaxf(tm, sv);
      }
      #pragma unroll
      for (int w = 1; w < 16; w <<= 1) tm = fmaxf(tm, __shfl_xor(tm, w));
      float mn = fmaxf(m_i[i], tm);
      float mb = (mn == NEG) ? 0.f : mn;             // guard fully-masked row
      float f = __expf(m_i[i] - mb);
      float ps = 0.f;
      #pragma unroll
      for (int j = 0; j < 4; j++) {
        float p = __expf(s[i][j] - mb);
        s[i][j] = p;
        ps += p;
      }
      #pragma unroll
      for (int w = 1; w < 16; w <<= 1) ps += __shfl_xor(ps, w);
      l_i[i] = l_i[i] * f + ps;
      m_i[i] = mn;
      #pragma unroll
      for (int j = 0; j < 4; j++) o_[i][j] *= f;
      #pragma unroll
      for (int j = 0; j < 4; j++) Ps[tq + i*16][tk + j*16] = s[i][j];
    }
    __syncthreads();

    // ---- PV: o[q][d] += P[q][kk] * V[kk][d] ----
    for (int kk = 0; kk < 64; kk++) {
      float pv[4], vv[4];
      #pragma unroll
      for (int i = 0; i < 4; i++) pv[i] = Ps[tq + i*16][kk];
      #pragma unroll
      for (int j = 0; j < 4; j++) vv[j] = Vs[kk][tk + j*16];
      #pragma unroll
      for (int i = 0; i < 4; i++)
        #pragma unroll
        for (int j = 0; j < 4; j++)
          o_[i][j] += pv[i] * vv[j];
    }
  }

  #pragma unroll
  for (int i = 0; i < 4; i++) {
    float inv = 1.f / l_i[i];
    int row = qt*64 + tq + i*16;
    #pragma unroll
    for (int j = 0; j < 4; j++) {
      int col = h*HD_ + tk + j*16;
      O[((size_t)(b * S_) + row) * HID_ + col] = (__bf16)(o_[i][j] * inv);
    }
  }
}

// ---------------- state = K^T V per head (partials over s) ---------
__global__ __launch_bounds__(256) void state_partial(
    const __bf16* __restrict__ K, const __bf16* __restrict__ V,
    float* __restrict__ part)
{
  __shared__ __bf16 Ksh[128][72];
  __shared__ __bf16 Vsh[128][72];
  const int bh = blockIdx.x;
  const int sc = blockIdx.y;
  const int b = bh >> 4, h = bh & 15;
  const int t = threadIdx.x;
  {
    int r = t >> 1;
    int c0 = (t & 1) * 32;
    const __bf16* kp = K + ((size_t)(b * S_) + sc*128 + r) * HID_ + h*HD_ + c0;
    const __bf16* vp = V + ((size_t)(b * S_) + sc*128 + r) * HID_ + h*HD_ + c0;
    #pragma unroll
    for (int u = 0; u < 4; u++) {
      *(bf16x8*)&Ksh[r][c0 + u*8] = *(const bf16x8*)(kp + u*8);
      *(bf16x8*)&Vsh[r][c0 + u*8] = *(const bf16x8*)(vp + u*8);
    }
  }
  __syncthreads();
  const int td = t >> 4, te = t & 15;
  float acc[4][4];
  #pragma unroll
  for (int i = 0; i < 4; i++)
    #pragma unroll
    for (int j = 0; j < 4; j++) acc[i][j] = 0.f;
  for (int s = 0; s < 128; s++) {
    float kd[4], ve[4];
    #pragma unroll
    for (int i = 0; i < 4; i++) kd[i] = (float)Ksh[s][td + i*16];
    #pragma unroll
    for (int j = 0; j < 4; j++) ve[j] = (float)Vsh[s][te + j*16];
    #pragma unroll
    for (int i = 0; i < 4; i++)
      #pragma unroll
      for (int j = 0; j < 4; j++)
        acc[i][j] += kd[i] * ve[j];
  }
  float* dst = part + (((size_t)bh * 16 + sc) << 12);
  #pragma unroll
  for (int i = 0; i < 4; i++)
    #pragma unroll
    for (int j = 0; j < 4; j++)
      dst[(td + i*16) * 64 + (te + j*16)] = acc[i][j];
}

__global__ __launch_bounds__(256) void state_reduce(
    const float* __restrict__ part, float* __restrict__ out)
{
  int i = blockIdx.x * 256 + threadIdx.x;   // 0..131071
  int bh = i >> 12, de = i & 4095;
  float s = 0.f;
  #pragma unroll
  for (int sc = 0; sc < 16; sc++) s += part[(((size_t)bh * 16 + sc) << 12) + de];
  out[i] = s;
}

// -------------------------------------------------------------------
extern "C" void kernel_launch(void* const* d_in, const int* in_sizes, int n_in,
                              void* d_out, int out_size, void* d_ws, size_t ws_size,
                              hipStream_t stream)
{
  const float* hs   = (const float*)d_in[0];
  const float* mask = (const float*)d_in[1];
  const float* Wq   = (const float*)d_in[2];
  const float* bq   = (const float*)d_in[3];
  const float* Wk   = (const float*)d_in[4];
  const float* bk   = (const float*)d_in[5];
  const float* Wv   = (const float*)d_in[6];
  const float* bv   = (const float*)d_in[7];
  const float* Wo   = (const float*)d_in[8];
  const float* bo   = (const float*)d_in[9];
  float* out = (float*)d_out;

  char* ws = (char*)d_ws;
  __bf16* Xb   = (__bf16*)(ws);                 // 8 MB  (4096x1024)
  __bf16* Wqb  = (__bf16*)(ws + (8u  << 20));   // 2 MB
  __bf16* Wkb  = (__bf16*)(ws + (10u << 20));
  __bf16* Wvb  = (__bf16*)(ws + (12u << 20));
  __bf16* Wob  = (__bf16*)(ws + (14u << 20));
  __bf16* Qb   = (__bf16*)(ws + (16u << 20));   // 8 MB each
  __bf16* Kb   = (__bf16*)(ws + (24u << 20));
  __bf16* Vb   = (__bf16*)(ws + (32u << 20));
  __bf16* Ob   = (__bf16*)(ws + (40u << 20));
  float*  part = (float*)(ws + (48u << 20));    // 8 MB (512 x 4096 f32)

  cast_bf16_kernel<<<4096, 256, 0, stream>>>(hs, Xb, (MTOK * HID_) / 4);
  cast_bf16_kernel<<<1024, 256, 0, stream>>>(Wq, Wqb, (HID_ * HID_) / 4);
  cast_bf16_kernel<<<1024, 256, 0, stream>>>(Wk, Wkb, (HID_ * HID_) / 4);
  cast_bf16_kernel<<<1024, 256, 0, stream>>>(Wv, Wvb, (HID_ * HID_) / 4);
  cast_bf16_kernel<<<1024, 256, 0, stream>>>(Wo, Wob, (HID_ * HID_) / 4);

  dim3 gg(HID_ / 128, MTOK / 128);   // (8, 32)
  gemm_bt<false><<<gg, 256, 0, stream>>>(Xb, Wqb, bq, nullptr, Qb, MTOK, HID_, HID_);
  gemm_bt<false><<<gg, 256, 0, stream>>>(Xb, Wkb, bk, mask,    Kb, MTOK, HID_, HID_);
  gemm_bt<false><<<gg, 256, 0, stream>>>(Xb, Wvb, bv, mask,    Vb, MTOK, HID_, HID_);

  flash_attn<<<dim3(S_ / 64, B_ * NH_), 256, 0, stream>>>(Qb, Kb, Vb, mask, Ob);

  gemm_bt<true><<<gg, 256, 0, stream>>>(Ob, Wob, bo, nullptr, out, MTOK, HID_, HID_);

  state_partial<<<dim3(B_ * NH_, 16), 256, 0, stream>>>(Kb, Vb, part);
  state_reduce<<<512, 256, 0, stream>>>(part, out + (size_t)MTOK * HID_);
}

// Round 2
// 248.965 us; speedup vs baseline: 3.1732x; 3.1732x over previous
//
#include <hip/hip_runtime.h>
#include <hip/hip_bf16.h>

#define B_ 2
#define S_ 2048
#define HID_ 1024
#define NH_ 16
#define HD_ 64
#define MTOK (B_*S_)

typedef __attribute__((ext_vector_type(8))) __bf16 bf16x8;
typedef __attribute__((ext_vector_type(4))) __bf16 bf16x4;
typedef __attribute__((ext_vector_type(4))) float f32x4;

// ---------------- f32 -> bf16 cast (vectorized x4) ----------------
__global__ __launch_bounds__(256) void cast_bf16_kernel(
    const float* __restrict__ in, __bf16* __restrict__ out, int n4)
{
  int i = blockIdx.x * 256 + threadIdx.x;
  if (i >= n4) return;
  float4 v = reinterpret_cast<const float4*>(in)[i];
  bf16x4 o;
  o[0] = (__bf16)v.x; o[1] = (__bf16)v.y; o[2] = (__bf16)v.z; o[3] = (__bf16)v.w;
  reinterpret_cast<bf16x4*>(out)[i] = o;
}

// ---------------- C = A @ W^T + bias, optional per-row scale -------
template<bool F32OUT>
__global__ __launch_bounds__(256) void gemm_bt(
    const __bf16* __restrict__ A, const __bf16* __restrict__ W,
    const float* __restrict__ bias, const float* __restrict__ rowscale,
    void* __restrict__ Cout, int M, int N, int K)
{
  __shared__ __bf16 As[128][40];
  __shared__ __bf16 Bs[128][40];
  const int t = threadIdx.x;
  const int m0 = blockIdx.y * 128;
  const int n0 = blockIdx.x * 128;
  const int lr = t >> 1;
  const int lc = (t & 1) * 16;
  const int lane = t & 63;
  const int wave = t >> 6;
  const int wr = (wave >> 1) * 64;
  const int wc = (wave & 1) * 64;
  const int fr = lane & 15;
  const int kg = lane >> 4;

  f32x4 acc[4][4];
  #pragma unroll
  for (int i = 0; i < 4; i++)
    #pragma unroll
    for (int j = 0; j < 4; j++) acc[i][j] = (f32x4)0.f;

  const __bf16* ap = A + (size_t)(m0 + lr) * K + lc;
  const __bf16* wp = W + (size_t)(n0 + lr) * K + lc;

  for (int k0 = 0; k0 < K; k0 += 32) {
    __syncthreads();
    *(bf16x8*)&As[lr][lc]     = *(const bf16x8*)(ap + k0);
    *(bf16x8*)&As[lr][lc + 8] = *(const bf16x8*)(ap + k0 + 8);
    *(bf16x8*)&Bs[lr][lc]     = *(const bf16x8*)(wp + k0);
    *(bf16x8*)&Bs[lr][lc + 8] = *(const bf16x8*)(wp + k0 + 8);
    __syncthreads();
    bf16x8 af[4], bf[4];
    #pragma unroll
    for (int m = 0; m < 4; m++) af[m] = *(const bf16x8*)&As[wr + m*16 + fr][kg*8];
    #pragma unroll
    for (int n = 0; n < 4; n++) bf[n] = *(const bf16x8*)&Bs[wc + n*16 + fr][kg*8];
    #pragma unroll
    for (int m = 0; m < 4; m++)
      #pragma unroll
      for (int n = 0; n < 4; n++)
        acc[m][n] = __builtin_amdgcn_mfma_f32_16x16x32_bf16(af[m], bf[n], acc[m][n], 0, 0, 0);
  }

  #pragma unroll
  for (int m = 0; m < 4; m++) {
    #pragma unroll
    for (int r = 0; r < 4; r++) {
      int row = m0 + wr + m*16 + kg*4 + r;
      float rs = rowscale ? rowscale[row] : 1.f;
      #pragma unroll
      for (int n = 0; n < 4; n++) {
        int col = n0 + wc + n*16 + fr;
        float v = (acc[m][n][r] + bias[col]) * rs;
        if (F32OUT) ((float*)Cout)[(size_t)row * N + col] = v;
        else        ((__bf16*)Cout)[(size_t)row * N + col] = (__bf16)v;
      }
    }
  }
}

// ---------------- bf16 transpose: [MTOK][HID] -> [HID][MTOK] ------
__global__ __launch_bounds__(256) void transpose_bf16(
    const __bf16* __restrict__ in, __bf16* __restrict__ out)
{
  __shared__ __bf16 tile[64][68];
  const int tok0 = blockIdx.x * 64;
  const int f0 = blockIdx.y * 64;
  const int t = threadIdx.x;
  const int r = t >> 2;
  const int c0 = (t & 3) * 16;
  const __bf16* src = in + (size_t)(tok0 + r) * HID_ + f0 + c0;
  *(bf16x8*)&tile[r][c0]     = *(const bf16x8*)src;
  *(bf16x8*)&tile[r][c0 + 8] = *(const bf16x8*)(src + 8);
  __syncthreads();
  bf16x8 o0, o1;
  #pragma unroll
  for (int j = 0; j < 8; j++) { o0[j] = tile[c0 + j][r]; o1[j] = tile[c0 + 8 + j][r]; }
  __bf16* dst = out + (size_t)(f0 + r) * MTOK + tok0 + c0;
  *(bf16x8*)dst = o0;
  *(bf16x8*)(dst + 8) = o1;
}

// ---------------- MFMA flash attention ----------------------------
// grid (32 bh, 16 qt), 512 threads = 8 waves; wave w owns q rows
// [qt*128 + w*16, +16). K tile 64 wide. LDS rows = 64 shorts (128B),
// XOR-swizzled: byte ^= (row&7)<<4.
#define SCALE_LOG2E 0.18033688011112043f  /* 0.125 * log2(e) */

__device__ __forceinline__ void gl16(__bf16* lds, const __bf16* g) {
  __builtin_amdgcn_global_load_lds(
      (const __attribute__((address_space(1))) void*)g,
      (__attribute__((address_space(3))) void*)lds, 16, 0, 0);
}
__device__ __forceinline__ bf16x8 ld_swz(const __bf16* base, int row, int xb) {
  return *(const bf16x8*)((const char*)base + row * 128 + (xb ^ ((row & 7) << 4)));
}
__device__ __forceinline__ void st_swz16(__bf16* base, int row, int colbyte, __bf16 v) {
  *(__bf16*)((char*)base + row * 128 + (colbyte ^ ((row & 7) << 4))) = v;
}

__global__ __launch_bounds__(512) void flash_mfma(
    const __bf16* __restrict__ Q, const __bf16* __restrict__ K,
    const __bf16* __restrict__ Vt, const float* __restrict__ mask,
    __bf16* __restrict__ O)
{
  __shared__ __bf16 Ks[64 * 64];        // [k_row][d] swizzled
  __shared__ __bf16 Vs[64 * 64];        // [d_row][kk] swizzled
  __shared__ __bf16 Ps[8][16 * 64];     // per-wave [q][kk] swizzled
  __shared__ float mk[64];

  const int bh = blockIdx.x;
  const int qt = (int)(gridDim.y - 1) - (int)blockIdx.y;  // big tiles first
  const int b = bh >> 4, h = bh & 15;
  const int t = threadIdx.x;
  const int w = t >> 6;
  const int lane = t & 63;
  const int fc = lane & 15;
  const int kg = lane >> 4;
  const int g4 = kg * 4;
  const float NEG = -__builtin_inff();

  const int q0w = qt * 128 + w * 16;
  const size_t tokbase = (size_t)b * S_;

  // ---- Q fragments (held in registers for whole kernel) ----
  bf16x8 qa[2];
  {
    const __bf16* qp = Q + (tokbase + q0w + fc) * HID_ + h * HD_;
    qa[0] = *(const bf16x8*)(qp + kg * 8);
    qa[1] = *(const bf16x8*)(qp + 32 + kg * 8);
  }

  f32x4 acc[4];
  float m_i[4], l_i[4];
  #pragma unroll
  for (int n = 0; n < 4; n++) acc[n] = (f32x4)0.f;
  #pragma unroll
  for (int r = 0; r < 4; r++) { m_i[r] = NEG; l_i[r] = 0.f; }

  __bf16* pw = &Ps[w][0];
  const int rr = lane >> 3;                       // 0..7
  const int cswz = ((lane & 7) ^ rr) * 8;         // pre-swizzled source col
  const int ktmax = 2 * qt + 1;

  for (int kt = 0; kt <= ktmax; ++kt) {
    // ---- stage K row-tile + Vt row-tile (each wave: 8 rows of each) ----
    gl16(&Ks[w * 512], K + (tokbase + (size_t)(kt * 64 + w * 8 + rr)) * HID_ + h * HD_ + cswz);
    gl16(&Vs[w * 512], Vt + (size_t)(h * HD_ + w * 8 + rr) * MTOK + tokbase + kt * 64 + cswz);
    if (t < 64) mk[t] = mask[tokbase + kt * 64 + t];
    __syncthreads();

    if (kt * 64 <= q0w + 15) {   // wave-uniform: any valid k in this tile
      // ---- QK^T: 16 q-rows x 64 k-cols ----
      f32x4 s[4];
      #pragma unroll
      for (int n = 0; n < 4; n++) s[n] = (f32x4)0.f;
      #pragma unroll
      for (int kd = 0; kd < 2; kd++)
        #pragma unroll
        for (int n = 0; n < 4; n++) {
          bf16x8 kf = ld_swz(Ks, n * 16 + fc, kd * 64 + kg * 16);
          s[n] = __builtin_amdgcn_mfma_f32_16x16x32_bf16(qa[kd], kf, s[n], 0, 0, 0);
        }

      // ---- online softmax (row group = 16 lanes sharing kg) ----
      bool okm[4];
      #pragma unroll
      for (int n = 0; n < 4; n++) okm[n] = (mk[n * 16 + fc] != 0.f);

      #pragma unroll
      for (int r = 0; r < 4; r++) {
        const int qg = q0w + g4 + r;
        float sv[4];
        float tm = NEG;
        #pragma unroll
        for (int n = 0; n < 4; n++) {
          bool ok = okm[n] && (kt * 64 + n * 16 + fc <= qg);
          sv[n] = ok ? s[n][r] * SCALE_LOG2E : NEG;
          tm = fmaxf(tm, sv[n]);
        }
        tm = fmaxf(tm, __shfl_xor(tm, 1));
        tm = fmaxf(tm, __shfl_xor(tm, 2));
        tm = fmaxf(tm, __shfl_xor(tm, 4));
        tm = fmaxf(tm, __shfl_xor(tm, 8));
        float mn = fmaxf(m_i[r], tm);
        float mb = (mn == NEG) ? 0.f : mn;
        float f = exp2f(m_i[r] - mb);
        float ps = 0.f;
        #pragma unroll
        for (int n = 0; n < 4; n++) {
          float p = exp2f(sv[n] - mb);
          ps += p;
          st_swz16(pw, g4 + r, (n * 16 + fc) * 2, (__bf16)p);
        }
        ps += __shfl_xor(ps, 1);
        ps += __shfl_xor(ps, 2);
        ps += __shfl_xor(ps, 4);
        ps += __shfl_xor(ps, 8);
        l_i[r] = l_i[r] * f + ps;
        m_i[r] = mn;
        #pragma unroll
        for (int n = 0; n < 4; n++) acc[n][r] *= f;
      }

      // ---- PV: O += P @ V  (A-frag from Ps, B-frag from Vs rows=d) ----
      #pragma unroll
      for (int kc = 0; kc < 2; kc++) {
        bf16x8 pf = ld_swz(pw, fc, kc * 64 + kg * 16);
        #pragma unroll
        for (int n = 0; n < 4; n++) {
          bf16x8 vf = ld_swz(Vs, n * 16 + fc, kc * 64 + kg * 16);
          acc[n] = __builtin_amdgcn_mfma_f32_16x16x32_bf16(pf, vf, acc[n], 0, 0, 0);
        }
      }
    }
    __syncthreads();
  }

  // ---- epilogue ----
  float inv[4];
  #pragma unroll
  for (int r = 0; r < 4; r++) inv[r] = 1.f / l_i[r];
  #pragma unroll
  for (int r = 0; r < 4; r++) {
    __bf16* op = O + (tokbase + q0w + g4 + r) * HID_ + h * HD_;
    #pragma unroll
    for (int n = 0; n < 4; n++)
      op[n * 16 + fc] = (__bf16)(acc[n][r] * inv[r]);
  }
}

// ---------------- state = K^T V per head (partials over s) ---------
__global__ __launch_bounds__(256) void state_partial(
    const __bf16* __restrict__ K, const __bf16* __restrict__ V,
    float* __restrict__ part)
{
  __shared__ __bf16 Ksh[128][72];
  __shared__ __bf16 Vsh[128][72];
  const int bh = blockIdx.x;
  const int sc = blockIdx.y;
  const int b = bh >> 4, h = bh & 15;
  const int t = threadIdx.x;
  {
    int r = t >> 1;
    int c0 = (t & 1) * 32;
    const __bf16* kp = K + ((size_t)(b * S_) + sc*128 + r) * HID_ + h*HD_ + c0;
    const __bf16* vp = V + ((size_t)(b * S_) + sc*128 + r) * HID_ + h*HD_ + c0;
    #pragma unroll
    for (int u = 0; u < 4; u++) {
      *(bf16x8*)&Ksh[r][c0 + u*8] = *(const bf16x8*)(kp + u*8);
      *(bf16x8*)&Vsh[r][c0 + u*8] = *(const bf16x8*)(vp + u*8);
    }
  }
  __syncthreads();
  const int td = t >> 4, te = t & 15;
  float acc[4][4];
  #pragma unroll
  for (int i = 0; i < 4; i++)
    #pragma unroll
    for (int j = 0; j < 4; j++) acc[i][j] = 0.f;
  for (int s = 0; s < 128; s++) {
    float kd[4], ve[4];
    #pragma unroll
    for (int i = 0; i < 4; i++) kd[i] = (float)Ksh[s][td + i*16];
    #pragma unroll
    for (int j = 0; j < 4; j++) ve[j] = (float)Vsh[s][te + j*16];
    #pragma unroll
    for (int i = 0; i < 4; i++)
      #pragma unroll
      for (int j = 0; j < 4; j++)
        acc[i][j] += kd[i] * ve[j];
  }
  float* dst = part + (((size_t)bh * 16 + sc) << 12);
  #pragma unroll
  for (int i = 0; i < 4; i++)
    #pragma unroll
    for (int j = 0; j < 4; j++)
      dst[(td + i*16) * 64 + (te + j*16)] = acc[i][j];
}

__global__ __launch_bounds__(256) void state_reduce(
    const float* __restrict__ part, float* __restrict__ out)
{
  int i = blockIdx.x * 256 + threadIdx.x;
  int bh = i >> 12, de = i & 4095;
  float s = 0.f;
  #pragma unroll
  for (int sc = 0; sc < 16; sc++) s += part[(((size_t)bh * 16 + sc) << 12) + de];
  out[i] = s;
}

// -------------------------------------------------------------------
extern "C" void kernel_launch(void* const* d_in, const int* in_sizes, int n_in,
                              void* d_out, int out_size, void* d_ws, size_t ws_size,
                              hipStream_t stream)
{
  const float* hs   = (const float*)d_in[0];
  const float* mask = (const float*)d_in[1];
  const float* Wq   = (const float*)d_in[2];
  const float* bq   = (const float*)d_in[3];
  const float* Wk   = (const float*)d_in[4];
  const float* bk   = (const float*)d_in[5];
  const float* Wv   = (const float*)d_in[6];
  const float* bv   = (const float*)d_in[7];
  const float* Wo   = (const float*)d_in[8];
  const float* bo   = (const float*)d_in[9];
  float* out = (float*)d_out;

  char* ws = (char*)d_ws;
  __bf16* Xb   = (__bf16*)(ws);                 // 8 MB; reused as Vt after proj
  __bf16* Wqb  = (__bf16*)(ws + (8u  << 20));
  __bf16* Wkb  = (__bf16*)(ws + (10u << 20));
  __bf16* Wvb  = (__bf16*)(ws + (12u << 20));
  __bf16* Wob  = (__bf16*)(ws + (14u << 20));
  __bf16* Qb   = (__bf16*)(ws + (16u << 20));
  __bf16* Kb   = (__bf16*)(ws + (24u << 20));
  __bf16* Vb   = (__bf16*)(ws + (32u << 20));
  __bf16* Ob   = (__bf16*)(ws + (40u << 20));
  float*  part = (float*)(ws + (48u << 20));

  cast_bf16_kernel<<<4096, 256, 0, stream>>>(hs, Xb, (MTOK * HID_) / 4);
  cast_bf16_kernel<<<1024, 256, 0, stream>>>(Wq, Wqb, (HID_ * HID_) / 4);
  cast_bf16_kernel<<<1024, 256, 0, stream>>>(Wk, Wkb, (HID_ * HID_) / 4);
  cast_bf16_kernel<<<1024, 256, 0, stream>>>(Wv, Wvb, (HID_ * HID_) / 4);
  cast_bf16_kernel<<<1024, 256, 0, stream>>>(Wo, Wob, (HID_ * HID_) / 4);

  dim3 gg(HID_ / 128, MTOK / 128);
  gemm_bt<false><<<gg, 256, 0, stream>>>(Xb, Wqb, bq, nullptr, Qb, MTOK, HID_, HID_);
  gemm_bt<false><<<gg, 256, 0, stream>>>(Xb, Wkb, bk, mask,    Kb, MTOK, HID_, HID_);
  gemm_bt<false><<<gg, 256, 0, stream>>>(Xb, Wvb, bv, mask,    Vb, MTOK, HID_, HID_);

  // Xb is dead now -> reuse as V^T [HID][MTOK]
  __bf16* Vtg = Xb;
  transpose_bf16<<<dim3(MTOK / 64, HID_ / 64), 256, 0, stream>>>(Vb, Vtg);

  flash_mfma<<<dim3(B_ * NH_, S_ / 128), 512, 0, stream>>>(Qb, Kb, Vtg, mask, Ob);

  gemm_bt<true><<<gg, 256, 0, stream>>>(Ob, Wob, bo, nullptr, out, MTOK, HID_, HID_);

  state_partial<<<dim3(B_ * NH_, 16), 256, 0, stream>>>(Kb, Vb, part);
  state_reduce<<<512, 256, 0, stream>>>(part, out + (size_t)MTOK * HID_);
}

// Round 3
// 152.314 us; speedup vs baseline: 5.1868x; 1.6346x over previous
//
#include <hip/hip_runtime.h>
#include <hip/hip_bf16.h>

#define B_ 2
#define S_ 2048
#define HID_ 1024
#define NH_ 16
#define HD_ 64
#define MTOK (B_*S_)
#define LDQKV 3072

typedef __attribute__((ext_vector_type(8))) __bf16 bf16x8;
typedef __attribute__((ext_vector_type(4))) __bf16 bf16x4;
typedef __attribute__((ext_vector_type(4))) float f32x4;

__device__ __forceinline__ void gl16(__bf16* lds, const __bf16* g) {
  __builtin_amdgcn_global_load_lds(
      (const __attribute__((address_space(1))) void*)g,
      (__attribute__((address_space(3))) void*)lds, 16, 0, 0);
}

// ---------------- fused f32 -> bf16 casts (one launch) -------------
// segments (in float4 units): X 1M | Wq 256K | Wk 256K | Wv 256K | Wo 256K
__global__ __launch_bounds__(256) void cast_all(
    const float* __restrict__ X,
    const float* __restrict__ Wq, const float* __restrict__ Wk,
    const float* __restrict__ Wv, const float* __restrict__ Wo,
    __bf16* __restrict__ Xb, __bf16* __restrict__ Wqkvb, __bf16* __restrict__ Wob)
{
  int i = blockIdx.x * 256 + threadIdx.x;
  const float* src; __bf16* dst; int j;
  if (i < (1 << 20))              { src = X;  dst = Xb;                 j = i; }
  else if (i < (1<<20)+(1<<18))   { src = Wq; dst = Wqkvb;              j = i - (1<<20); }
  else if (i < (1<<20)+(2<<18))   { src = Wk; dst = Wqkvb + (1<<20);    j = i - (1<<20) - (1<<18); }
  else if (i < (1<<20)+(3<<18))   { src = Wv; dst = Wqkvb + (2<<20);    j = i - (1<<20) - (2<<18); }
  else                            { src = Wo; dst = Wob;                j = i - (1<<20) - (3<<18); }
  float4 v = reinterpret_cast<const float4*>(src)[j];
  bf16x4 o;
  o[0] = (__bf16)v.x; o[1] = (__bf16)v.y; o[2] = (__bf16)v.z; o[3] = (__bf16)v.w;
  reinterpret_cast<bf16x4*>(dst)[j] = o;
}

// ---------------- QKV projection: C = X @ Wqkv^T (+bias, K/V masked)
// X [4096][1024], Wqkv [3072][1024], C [4096][3072] bf16. 128x128 tile.
__global__ __launch_bounds__(256) void gemm_qkv(
    const __bf16* __restrict__ A, const __bf16* __restrict__ W,
    const float* __restrict__ bq, const float* __restrict__ bk,
    const float* __restrict__ bv, const float* __restrict__ mask,
    __bf16* __restrict__ C)
{
  __shared__ __bf16 As[128 * 32];
  __shared__ __bf16 Bs[128 * 32];
  const int t = threadIdx.x;
  const int m0 = blockIdx.y * 128;
  const int n0 = blockIdx.x * 128;
  const int lane = t & 63;
  const int w = t >> 6;
  const int wr = (w >> 1) * 64;
  const int wc = (w & 1) * 64;
  const int fr = lane & 15;
  const int kg = lane >> 4;

  f32x4 acc[4][4];
  #pragma unroll
  for (int i = 0; i < 4; i++)
    #pragma unroll
    for (int j = 0; j < 4; j++) acc[i][j] = (f32x4)0.f;

  const int srow = w * 16 + (lane >> 2);
  const int scol = (lane & 3) * 8;
  const __bf16* ap0 = A + (size_t)(m0 + srow) * HID_ + scol;
  const __bf16* ap1 = A + (size_t)(m0 + 64 + srow) * HID_ + scol;
  const __bf16* wp0 = W + (size_t)(n0 + srow) * HID_ + scol;
  const __bf16* wp1 = W + (size_t)(n0 + 64 + srow) * HID_ + scol;

  for (int k0 = 0; k0 < HID_; k0 += 32) {
    __syncthreads();
    gl16(&As[w * 512], ap0 + k0);
    gl16(&As[2048 + w * 512], ap1 + k0);
    gl16(&Bs[w * 512], wp0 + k0);
    gl16(&Bs[2048 + w * 512], wp1 + k0);
    __syncthreads();
    bf16x8 af[4], bf[4];
    #pragma unroll
    for (int m = 0; m < 4; m++) af[m] = *(const bf16x8*)&As[(wr + m*16 + fr) * 32 + kg*8];
    #pragma unroll
    for (int n = 0; n < 4; n++) bf[n] = *(const bf16x8*)&Bs[(wc + n*16 + fr) * 32 + kg*8];
    #pragma unroll
    for (int m = 0; m < 4; m++)
      #pragma unroll
      for (int n = 0; n < 4; n++)
        acc[m][n] = __builtin_amdgcn_mfma_f32_16x16x32_bf16(af[m], bf[n], acc[m][n], 0, 0, 0);
  }

  const int region = n0 >> 10;                 // 0=Q 1=K 2=V (uniform per block)
  const float* bias = region == 0 ? bq : (region == 1 ? bk : bv);
  const int nloc = n0 & 1023;

  #pragma unroll
  for (int m = 0; m < 4; m++) {
    #pragma unroll
    for (int r = 0; r < 4; r++) {
      int row = m0 + wr + m*16 + kg*4 + r;
      float rs = region ? mask[row] : 1.f;
      #pragma unroll
      for (int n = 0; n < 4; n++) {
        int c = wc + n*16 + fr;
        float v = (acc[m][n][r] + bias[nloc + c]) * rs;
        C[(size_t)row * LDQKV + n0 + c] = (__bf16)v;
      }
    }
  }
}

// ---------------- O projection: out = Ob @ Wo^T + bo (f32 out) ----
__global__ __launch_bounds__(256) void gemm_o(
    const __bf16* __restrict__ A, const __bf16* __restrict__ W,
    const float* __restrict__ bias, float* __restrict__ C)
{
  __shared__ __bf16 As[128 * 32];
  __shared__ __bf16 Bs[128 * 32];
  const int t = threadIdx.x;
  const int m0 = blockIdx.y * 128;
  const int n0 = blockIdx.x * 128;
  const int lane = t & 63;
  const int w = t >> 6;
  const int wr = (w >> 1) * 64;
  const int wc = (w & 1) * 64;
  const int fr = lane & 15;
  const int kg = lane >> 4;

  f32x4 acc[4][4];
  #pragma unroll
  for (int i = 0; i < 4; i++)
    #pragma unroll
    for (int j = 0; j < 4; j++) acc[i][j] = (f32x4)0.f;

  const int srow = w * 16 + (lane >> 2);
  const int scol = (lane & 3) * 8;
  const __bf16* ap0 = A + (size_t)(m0 + srow) * HID_ + scol;
  const __bf16* ap1 = A + (size_t)(m0 + 64 + srow) * HID_ + scol;
  const __bf16* wp0 = W + (size_t)(n0 + srow) * HID_ + scol;
  const __bf16* wp1 = W + (size_t)(n0 + 64 + srow) * HID_ + scol;

  for (int k0 = 0; k0 < HID_; k0 += 32) {
    __syncthreads();
    gl16(&As[w * 512], ap0 + k0);
    gl16(&As[2048 + w * 512], ap1 + k0);
    gl16(&Bs[w * 512], wp0 + k0);
    gl16(&Bs[2048 + w * 512], wp1 + k0);
    __syncthreads();
    bf16x8 af[4], bf[4];
    #pragma unroll
    for (int m = 0; m < 4; m++) af[m] = *(const bf16x8*)&As[(wr + m*16 + fr) * 32 + kg*8];
    #pragma unroll
    for (int n = 0; n < 4; n++) bf[n] = *(const bf16x8*)&Bs[(wc + n*16 + fr) * 32 + kg*8];
    #pragma unroll
    for (int m = 0; m < 4; m++)
      #pragma unroll
      for (int n = 0; n < 4; n++)
        acc[m][n] = __builtin_amdgcn_mfma_f32_16x16x32_bf16(af[m], bf[n], acc[m][n], 0, 0, 0);
  }

  #pragma unroll
  for (int m = 0; m < 4; m++) {
    #pragma unroll
    for (int r = 0; r < 4; r++) {
      int row = m0 + wr + m*16 + kg*4 + r;
      #pragma unroll
      for (int n = 0; n < 4; n++) {
        int col = n0 + wc + n*16 + fr;
        C[(size_t)row * HID_ + col] = acc[m][n][r] + bias[col];
      }
    }
  }
}

// ---------------- bf16 transpose (strided in): -> [HID][MTOK] -----
__global__ __launch_bounds__(256) void transpose_bf16(
    const __bf16* __restrict__ in, int ldin, __bf16* __restrict__ out)
{
  __shared__ __bf16 tile[64][68];
  const int tok0 = blockIdx.x * 64;
  const int f0 = blockIdx.y * 64;
  const int t = threadIdx.x;
  const int r = t >> 2;
  const int c0 = (t & 3) * 16;
  const __bf16* src = in + (size_t)(tok0 + r) * ldin + f0 + c0;
  *(bf16x8*)&tile[r][c0]     = *(const bf16x8*)src;
  *(bf16x8*)&tile[r][c0 + 8] = *(const bf16x8*)(src + 8);
  __syncthreads();
  bf16x8 o0, o1;
  #pragma unroll
  for (int j = 0; j < 8; j++) { o0[j] = tile[c0 + j][r]; o1[j] = tile[c0 + 8 + j][r]; }
  __bf16* dst = out + (size_t)(f0 + r) * MTOK + tok0 + c0;
  *(bf16x8*)dst = o0;
  *(bf16x8*)(dst + 8) = o1;
}

// ---------------- MFMA flash attention, fixed-max softmax ----------
#define SCALE_LOG2E 0.18033688011112043f  /* 0.125 * log2(e) */

__device__ __forceinline__ bf16x8 ld_swz(const __bf16* base, int row, int xb) {
  return *(const bf16x8*)((const char*)base + row * 128 + (xb ^ ((row & 7) << 4)));
}
__device__ __forceinline__ void st_swz16(__bf16* base, int row, int colbyte, __bf16 v) {
  *(__bf16*)((char*)base + row * 128 + (colbyte ^ ((row & 7) << 4))) = v;
}

__global__ __launch_bounds__(512) void flash_mfma(
    const __bf16* __restrict__ Q, const __bf16* __restrict__ K,
    const __bf16* __restrict__ Vt, const float* __restrict__ mask,
    __bf16* __restrict__ O)
{
  __shared__ __bf16 Ks[64 * 64];        // [k_row][d] swizzled
  __shared__ __bf16 Vs[64 * 64];        // [d_row][kk] swizzled
  __shared__ __bf16 Ps[8][16 * 64];     // per-wave [q][kk] swizzled
  __shared__ float mk[64];

  const int bh = blockIdx.x;
  const int qt = (int)(gridDim.y - 1) - (int)blockIdx.y;  // big tiles first
  const int b = bh >> 4, h = bh & 15;
  const int t = threadIdx.x;
  const int w = t >> 6;
  const int lane = t & 63;
  const int fc = lane & 15;
  const int kg = lane >> 4;
  const int g4 = kg * 4;

  const int q0w = qt * 128 + w * 16;
  const size_t tokbase = (size_t)b * S_;

  bf16x8 qa[2];
  {
    const __bf16* qp = Q + (tokbase + q0w + fc) * LDQKV + h * HD_;
    qa[0] = *(const bf16x8*)(qp + kg * 8);
    qa[1] = *(const bf16x8*)(qp + 32 + kg * 8);
  }

  bf16x8 ones;
  #pragma unroll
  for (int j = 0; j < 8; j++) ones[j] = (__bf16)1.f;

  f32x4 acc[4], accl;
  #pragma unroll
  for (int n = 0; n < 4; n++) acc[n] = (f32x4)0.f;
  accl = (f32x4)0.f;

  __bf16* pw = &Ps[w][0];
  const int rr = lane >> 3;
  const int cswz = ((lane & 7) ^ rr) * 8;
  const int ktmax = 2 * qt + 1;

  for (int kt = 0; kt <= ktmax; ++kt) {
    gl16(&Ks[w * 512], K + (tokbase + (size_t)(kt * 64 + w * 8 + rr)) * LDQKV + h * HD_ + cswz);
    gl16(&Vs[w * 512], Vt + (size_t)(h * HD_ + w * 8 + rr) * MTOK + tokbase + kt * 64 + cswz);
    if (t < 64) mk[t] = mask[tokbase + kt * 64 + t];
    __syncthreads();

    if (kt * 64 <= q0w + 15) {
      // ---- QK^T ----
      f32x4 s[4];
      #pragma unroll
      for (int n = 0; n < 4; n++) s[n] = (f32x4)0.f;
      #pragma unroll
      for (int kd = 0; kd < 2; kd++)
        #pragma unroll
        for (int n = 0; n < 4; n++) {
          bf16x8 kf = ld_swz(Ks, n * 16 + fc, kd * 64 + kg * 16);
          s[n] = __builtin_amdgcn_mfma_f32_16x16x32_bf16(qa[kd], kf, s[n], 0, 0, 0);
        }

      // ---- fixed-max softmax: P = exp2(s*scale) masked, straight to LDS ----
      bool okm[4];
      #pragma unroll
      for (int n = 0; n < 4; n++) okm[n] = (mk[n * 16 + fc] != 0.f);

      #pragma unroll
      for (int r = 0; r < 4; r++) {
        const int qg = q0w + g4 + r;
        #pragma unroll
        for (int n = 0; n < 4; n++) {
          bool ok = okm[n] && (kt * 64 + n * 16 + fc <= qg);
          float p = ok ? exp2f(s[n][r] * SCALE_LOG2E) : 0.f;
          st_swz16(pw, g4 + r, (n * 16 + fc) * 2, (__bf16)p);
        }
      }

      // ---- PV (+ row-sum l via ones-MFMA, no cross-lane reduce) ----
      #pragma unroll
      for (int kc = 0; kc < 2; kc++) {
        bf16x8 pf = ld_swz(pw, fc, kc * 64 + kg * 16);
        accl = __builtin_amdgcn_mfma_f32_16x16x32_bf16(pf, ones, accl, 0, 0, 0);
        #pragma unroll
        for (int n = 0; n < 4; n++) {
          bf16x8 vf = ld_swz(Vs, n * 16 + fc, kc * 64 + kg * 16);
          acc[n] = __builtin_amdgcn_mfma_f32_16x16x32_bf16(pf, vf, acc[n], 0, 0, 0);
        }
      }
    }
    __syncthreads();
  }

  #pragma unroll
  for (int r = 0; r < 4; r++) {
    float inv = accl[r] > 0.f ? 1.f / accl[r] : 0.f;
    __bf16* op = O + (tokbase + q0w + g4 + r) * HID_ + h * HD_;
    #pragma unroll
    for (int n = 0; n < 4; n++)
      op[n * 16 + fc] = (__bf16)(acc[n][r] * inv);
  }
}

// ---------------- state = K^T V per head (partials over s) ---------
__global__ __launch_bounds__(256) void state_partial(
    const __bf16* __restrict__ K, const __bf16* __restrict__ V, int ld,
    float* __restrict__ part)
{
  __shared__ __bf16 Ksh[128][72];
  __shared__ __bf16 Vsh[128][72];
  const int bh = blockIdx.x;
  const int sc = blockIdx.y;
  const int b = bh >> 4, h = bh & 15;
  const int t = threadIdx.x;
  {
    int r = t >> 1;
    int c0 = (t & 1) * 32;
    const __bf16* kp = K + ((size_t)(b * S_) + sc*128 + r) * ld + h*HD_ + c0;
    const __bf16* vp = V + ((size_t)(b * S_) + sc*128 + r) * ld + h*HD_ + c0;
    #pragma unroll
    for (int u = 0; u < 4; u++) {
      *(bf16x8*)&Ksh[r][c0 + u*8] = *(const bf16x8*)(kp + u*8);
      *(bf16x8*)&Vsh[r][c0 + u*8] = *(const bf16x8*)(vp + u*8);
    }
  }
  __syncthreads();
  const int td = t >> 4, te = t & 15;
  float acc[4][4];
  #pragma unroll
  for (int i = 0; i < 4; i++)
    #pragma unroll
    for (int j = 0; j < 4; j++) acc[i][j] = 0.f;
  for (int s = 0; s < 128; s++) {
    float kd[4], ve[4];
    #pragma unroll
    for (int i = 0; i < 4; i++) kd[i] = (float)Ksh[s][td + i*16];
    #pragma unroll
    for (int j = 0; j < 4; j++) ve[j] = (float)Vsh[s][te + j*16];
    #pragma unroll
    for (int i = 0; i < 4; i++)
      #pragma unroll
      for (int j = 0; j < 4; j++)
        acc[i][j] += kd[i] * ve[j];
  }
  float* dst = part + (((size_t)bh * 16 + sc) << 12);
  #pragma unroll
  for (int i = 0; i < 4; i++)
    #pragma unroll
    for (int j = 0; j < 4; j++)
      dst[(td + i*16) * 64 + (te + j*16)] = acc[i][j];
}

__global__ __launch_bounds__(256) void state_reduce(
    const float* __restrict__ part, float* __restrict__ out)
{
  int i = blockIdx.x * 256 + threadIdx.x;
  int bh = i >> 12, de = i & 4095;
  float s = 0.f;
  #pragma unroll
  for (int sc = 0; sc < 16; sc++) s += part[(((size_t)bh * 16 + sc) << 12) + de];
  out[i] = s;
}

// -------------------------------------------------------------------
extern "C" void kernel_launch(void* const* d_in, const int* in_sizes, int n_in,
                              void* d_out, int out_size, void* d_ws, size_t ws_size,
                              hipStream_t stream)
{
  const float* hs   = (const float*)d_in[0];
  const float* mask = (const float*)d_in[1];
  const float* Wq   = (const float*)d_in[2];
  const float* bq   = (const float*)d_in[3];
  const float* Wk   = (const float*)d_in[4];
  const float* bk   = (const float*)d_in[5];
  const float* Wv   = (const float*)d_in[6];
  const float* bv   = (const float*)d_in[7];
  const float* Wo   = (const float*)d_in[8];
  const float* bo   = (const float*)d_in[9];
  float* out = (float*)d_out;

  char* ws = (char*)d_ws;
  __bf16* Wqkvb = (__bf16*)(ws);                 // 6 MB [3072][1024]
  __bf16* Wob   = (__bf16*)(ws + (6u  << 20));   // 2 MB
  __bf16* Xb    = (__bf16*)(ws + (8u  << 20));   // 8 MB; reused as Vt
  __bf16* QKV   = (__bf16*)(ws + (16u << 20));   // 24 MB [4096][3072]
  __bf16* Ob    = (__bf16*)(ws + (40u << 20));   // 8 MB
  float*  part  = (float*)(ws + (48u << 20));    // 8 MB

  cast_all<<<8192, 256, 0, stream>>>(hs, Wq, Wk, Wv, Wo, Xb, Wqkvb, Wob);

  gemm_qkv<<<dim3(LDQKV / 128, MTOK / 128), 256, 0, stream>>>(
      Xb, Wqkvb, bq, bk, bv, mask, QKV);

  // Xb dead -> reuse as V^T [HID][MTOK]
  __bf16* Vtg = Xb;
  transpose_bf16<<<dim3(MTOK / 64, HID_ / 64), 256, 0, stream>>>(QKV + 2048, LDQKV, Vtg);

  flash_mfma<<<dim3(B_ * NH_, S_ / 128), 512, 0, stream>>>(
      QKV, QKV + 1024, Vtg, mask, Ob);

  gemm_o<<<dim3(HID_ / 128, MTOK / 128), 256, 0, stream>>>(Ob, Wob, bo, out);

  state_partial<<<dim3(B_ * NH_, 16), 256, 0, stream>>>(
      QKV + 1024, QKV + 2048, LDQKV, part);
  state_reduce<<<512, 256, 0, stream>>>(part, out + (size_t)MTOK * HID_);
}

// Round 4
// 144.067 us; speedup vs baseline: 5.4837x; 1.0572x over previous
//
#include <hip/hip_runtime.h>
#include <hip/hip_bf16.h>

#define B_ 2
#define S_ 2048
#define HID_ 1024
#define NH_ 16
#define HD_ 64
#define MTOK (B_*S_)
#define LDQKV 3072

typedef __attribute__((ext_vector_type(8))) __bf16 bf16x8;
typedef __attribute__((ext_vector_type(4))) __bf16 bf16x4;
typedef __attribute__((ext_vector_type(4))) float f32x4;

__device__ __forceinline__ void gl16(__bf16* lds, const __bf16* g) {
  __builtin_amdgcn_global_load_lds(
      (const __attribute__((address_space(1))) void*)g,
      (__attribute__((address_space(3))) void*)lds, 16, 0, 0);
}
__device__ __forceinline__ void gl4(float* lds, const float* g) {
  __builtin_amdgcn_global_load_lds(
      (const __attribute__((address_space(1))) void*)g,
      (__attribute__((address_space(3))) void*)lds, 4, 0, 0);
}

// ---------------- fused f32 -> bf16 casts (one launch) -------------
__global__ __launch_bounds__(256) void cast_all(
    const float* __restrict__ X,
    const float* __restrict__ Wq, const float* __restrict__ Wk,
    const float* __restrict__ Wv, const float* __restrict__ Wo,
    __bf16* __restrict__ Xb, __bf16* __restrict__ Wqkvb, __bf16* __restrict__ Wob)
{
  int i = blockIdx.x * 256 + threadIdx.x;
  const float* src; __bf16* dst; int j;
  if (i < (1 << 20))              { src = X;  dst = Xb;                 j = i; }
  else if (i < (1<<20)+(1<<18))   { src = Wq; dst = Wqkvb;              j = i - (1<<20); }
  else if (i < (1<<20)+(2<<18))   { src = Wk; dst = Wqkvb + (1<<20);    j = i - (1<<20) - (1<<18); }
  else if (i < (1<<20)+(3<<18))   { src = Wv; dst = Wqkvb + (2<<20);    j = i - (1<<20) - (2<<18); }
  else                            { src = Wo; dst = Wob;                j = i - (1<<20) - (3<<18); }
  float4 v = reinterpret_cast<const float4*>(src)[j];
  bf16x4 o;
  o[0] = (__bf16)v.x; o[1] = (__bf16)v.y; o[2] = (__bf16)v.z; o[3] = (__bf16)v.w;
  reinterpret_cast<bf16x4*>(dst)[j] = o;
}

// ---------------- QKV projection: C = X @ Wqkv^T (+bias, K/V masked)
__global__ __launch_bounds__(256) void gemm_qkv(
    const __bf16* __restrict__ A, const __bf16* __restrict__ W,
    const float* __restrict__ bq, const float* __restrict__ bk,
    const float* __restrict__ bv, const float* __restrict__ mask,
    __bf16* __restrict__ C)
{
  __shared__ __bf16 As[128 * 32];
  __shared__ __bf16 Bs[128 * 32];
  const int t = threadIdx.x;
  const int m0 = blockIdx.y * 128;
  const int n0 = blockIdx.x * 128;
  const int lane = t & 63;
  const int w = t >> 6;
  const int wr = (w >> 1) * 64;
  const int wc = (w & 1) * 64;
  const int fr = lane & 15;
  const int kg = lane >> 4;

  f32x4 acc[4][4];
  #pragma unroll
  for (int i = 0; i < 4; i++)
    #pragma unroll
    for (int j = 0; j < 4; j++) acc[i][j] = (f32x4)0.f;

  const int srow = w * 16 + (lane >> 2);
  const int scol = (lane & 3) * 8;
  const __bf16* ap0 = A + (size_t)(m0 + srow) * HID_ + scol;
  const __bf16* ap1 = A + (size_t)(m0 + 64 + srow) * HID_ + scol;
  const __bf16* wp0 = W + (size_t)(n0 + srow) * HID_ + scol;
  const __bf16* wp1 = W + (size_t)(n0 + 64 + srow) * HID_ + scol;

  for (int k0 = 0; k0 < HID_; k0 += 32) {
    __syncthreads();
    gl16(&As[w * 512], ap0 + k0);
    gl16(&As[2048 + w * 512], ap1 + k0);
    gl16(&Bs[w * 512], wp0 + k0);
    gl16(&Bs[2048 + w * 512], wp1 + k0);
    __syncthreads();
    bf16x8 af[4], bf[4];
    #pragma unroll
    for (int m = 0; m < 4; m++) af[m] = *(const bf16x8*)&As[(wr + m*16 + fr) * 32 + kg*8];
    #pragma unroll
    for (int n = 0; n < 4; n++) bf[n] = *(const bf16x8*)&Bs[(wc + n*16 + fr) * 32 + kg*8];
    #pragma unroll
    for (int m = 0; m < 4; m++)
      #pragma unroll
      for (int n = 0; n < 4; n++)
        acc[m][n] = __builtin_amdgcn_mfma_f32_16x16x32_bf16(af[m], bf[n], acc[m][n], 0, 0, 0);
  }

  const int region = n0 >> 10;
  const float* bias = region == 0 ? bq : (region == 1 ? bk : bv);
  const int nloc = n0 & 1023;

  #pragma unroll
  for (int m = 0; m < 4; m++) {
    #pragma unroll
    for (int r = 0; r < 4; r++) {
      int row = m0 + wr + m*16 + kg*4 + r;
      float rs = region ? mask[row] : 1.f;
      #pragma unroll
      for (int n = 0; n < 4; n++) {
        int c = wc + n*16 + fr;
        float v = (acc[m][n][r] + bias[nloc + c]) * rs;
        C[(size_t)row * LDQKV + n0 + c] = (__bf16)v;
      }
    }
  }
}

// ---------------- O projection: out = Ob @ Wo^T + bo (f32 out) ----
__global__ __launch_bounds__(256) void gemm_o(
    const __bf16* __restrict__ A, const __bf16* __restrict__ W,
    const float* __restrict__ bias, float* __restrict__ C)
{
  __shared__ __bf16 As[128 * 32];
  __shared__ __bf16 Bs[128 * 32];
  const int t = threadIdx.x;
  const int m0 = blockIdx.y * 128;
  const int n0 = blockIdx.x * 128;
  const int lane = t & 63;
  const int w = t >> 6;
  const int wr = (w >> 1) * 64;
  const int wc = (w & 1) * 64;
  const int fr = lane & 15;
  const int kg = lane >> 4;

  f32x4 acc[4][4];
  #pragma unroll
  for (int i = 0; i < 4; i++)
    #pragma unroll
    for (int j = 0; j < 4; j++) acc[i][j] = (f32x4)0.f;

  const int srow = w * 16 + (lane >> 2);
  const int scol = (lane & 3) * 8;
  const __bf16* ap0 = A + (size_t)(m0 + srow) * HID_ + scol;
  const __bf16* ap1 = A + (size_t)(m0 + 64 + srow) * HID_ + scol;
  const __bf16* wp0 = W + (size_t)(n0 + srow) * HID_ + scol;
  const __bf16* wp1 = W + (size_t)(n0 + 64 + srow) * HID_ + scol;

  for (int k0 = 0; k0 < HID_; k0 += 32) {
    __syncthreads();
    gl16(&As[w * 512], ap0 + k0);
    gl16(&As[2048 + w * 512], ap1 + k0);
    gl16(&Bs[w * 512], wp0 + k0);
    gl16(&Bs[2048 + w * 512], wp1 + k0);
    __syncthreads();
    bf16x8 af[4], bf[4];
    #pragma unroll
    for (int m = 0; m < 4; m++) af[m] = *(const bf16x8*)&As[(wr + m*16 + fr) * 32 + kg*8];
    #pragma unroll
    for (int n = 0; n < 4; n++) bf[n] = *(const bf16x8*)&Bs[(wc + n*16 + fr) * 32 + kg*8];
    #pragma unroll
    for (int m = 0; m < 4; m++)
      #pragma unroll
      for (int n = 0; n < 4; n++)
        acc[m][n] = __builtin_amdgcn_mfma_f32_16x16x32_bf16(af[m], bf[n], acc[m][n], 0, 0, 0);
  }

  #pragma unroll
  for (int m = 0; m < 4; m++) {
    #pragma unroll
    for (int r = 0; r < 4; r++) {
      int row = m0 + wr + m*16 + kg*4 + r;
      #pragma unroll
      for (int n = 0; n < 4; n++) {
        int col = n0 + wc + n*16 + fr;
        C[(size_t)row * HID_ + col] = acc[m][n][r] + bias[col];
      }
    }
  }
}

// ---------------- bf16 transpose (strided in): -> [feat][MTOK] ----
__global__ __launch_bounds__(256) void transpose_bf16(
    const __bf16* __restrict__ in, int ldin, __bf16* __restrict__ out)
{
  __shared__ __bf16 tile[64][68];
  const int tok0 = blockIdx.x * 64;
  const int f0 = blockIdx.y * 64;
  const int t = threadIdx.x;
  const int r = t >> 2;
  const int c0 = (t & 3) * 16;
  const __bf16* src = in + (size_t)(tok0 + r) * ldin + f0 + c0;
  *(bf16x8*)&tile[r][c0]     = *(const bf16x8*)src;
  *(bf16x8*)&tile[r][c0 + 8] = *(const bf16x8*)(src + 8);
  __syncthreads();
  bf16x8 o0, o1;
  #pragma unroll
  for (int j = 0; j < 8; j++) { o0[j] = tile[c0 + j][r]; o1[j] = tile[c0 + 8 + j][r]; }
  __bf16* dst = out + (size_t)(f0 + r) * MTOK + tok0 + c0;
  *(bf16x8*)dst = o0;
  *(bf16x8*)(dst + 8) = o1;
}

// ---------------- MFMA flash attention, double-buffered -----------
#define SCALE_LOG2E 0.18033688011112043f  /* 0.125 * log2(e) */

__device__ __forceinline__ bf16x8 ld_swz(const __bf16* base, int row, int xb) {
  return *(const bf16x8*)((const char*)base + row * 128 + (xb ^ ((row & 7) << 4)));
}
__device__ __forceinline__ void st_swz16(__bf16* base, int row, int colbyte, __bf16 v) {
  *(__bf16*)((char*)base + row * 128 + (colbyte ^ ((row & 7) << 4))) = v;
}
__device__ __forceinline__ bf16x8 ld_swz256(const __bf16* base, int row, int xb) {
  return *(const bf16x8*)((const char*)base + row * 256 + (xb ^ ((row & 7) << 4)));
}

__global__ __launch_bounds__(512) void flash_mfma(
    const __bf16* __restrict__ Q, const __bf16* __restrict__ K,
    const __bf16* __restrict__ Vt, const float* __restrict__ mask,
    __bf16* __restrict__ O)
{
  __shared__ __bf16 Ks[2][64 * 64];     // [k_row][d] swizzled, 128B rows
  __shared__ __bf16 Vs[2][64 * 64];     // [d_row][kk] swizzled
  __shared__ __bf16 Ps[8][16 * 64];     // per-wave [q][kk] swizzled
  __shared__ float mk[2][64];

  const int bh = blockIdx.x;
  const int qt = (int)(gridDim.y - 1) - (int)blockIdx.y;  // big tiles first
  const int b = bh >> 4, h = bh & 15;
  const int t = threadIdx.x;
  const int w = t >> 6;
  const int lane = t & 63;
  const int fc = lane & 15;
  const int kg = lane >> 4;
  const int g4 = kg * 4;

  const int q0w = qt * 128 + w * 16;
  const size_t tokbase = (size_t)b * S_;

  const int rr = lane >> 3;
  const int cswz = ((lane & 7) ^ rr) * 8;     // shorts, pre-swizzled source col
  const int ktmax = 2 * qt + 1;

  // ---- prologue: stage tile 0 into buffer 0 ----
  gl16(&Ks[0][w * 512], K + (tokbase + (size_t)(w * 8 + rr)) * LDQKV + h * HD_ + cswz);
  gl16(&Vs[0][w * 512], Vt + (size_t)(h * HD_ + w * 8 + rr) * MTOK + tokbase + cswz);
  gl4(&mk[0][0], mask + tokbase + lane);

  bf16x8 qa[2];
  {
    const __bf16* qp = Q + (tokbase + q0w + fc) * LDQKV + h * HD_;
    qa[0] = *(const bf16x8*)(qp + kg * 8);
    qa[1] = *(const bf16x8*)(qp + 32 + kg * 8);
  }

  bf16x8 ones;
  #pragma unroll
  for (int j = 0; j < 8; j++) ones[j] = (__bf16)1.f;

  f32x4 acc[4], accl;
  #pragma unroll
  for (int n = 0; n < 4; n++) acc[n] = (f32x4)0.f;
  accl = (f32x4)0.f;

  __bf16* pw = &Ps[w][0];

  for (int kt = 0; kt <= ktmax; ++kt) {
    const int cur = kt & 1;
    if (kt < ktmax) {   // prefetch next tile into other buffer
      const int nxt = cur ^ 1;
      gl16(&Ks[nxt][w * 512],
           K + (tokbase + (size_t)((kt + 1) * 64 + w * 8 + rr)) * LDQKV + h * HD_ + cswz);
      gl16(&Vs[nxt][w * 512],
           Vt + (size_t)(h * HD_ + w * 8 + rr) * MTOK + tokbase + (kt + 1) * 64 + cswz);
      gl4(&mk[nxt][0], mask + tokbase + (kt + 1) * 64 + lane);
      asm volatile("s_waitcnt vmcnt(3)" ::: "memory");   // cur's 3 loads done
    } else {
      asm volatile("s_waitcnt vmcnt(0)" ::: "memory");
    }
    __builtin_amdgcn_sched_barrier(0);
    __builtin_amdgcn_s_barrier();

    if (kt * 64 <= q0w + 15) {
      const __bf16* ks = &Ks[cur][0];
      const __bf16* vs = &Vs[cur][0];
      // ---- QK^T ----
      f32x4 s[4];
      #pragma unroll
      for (int n = 0; n < 4; n++) s[n] = (f32x4)0.f;
      #pragma unroll
      for (int kd = 0; kd < 2; kd++)
        #pragma unroll
        for (int n = 0; n < 4; n++) {
          bf16x8 kf = ld_swz(ks, n * 16 + fc, kd * 64 + kg * 16);
          s[n] = __builtin_amdgcn_mfma_f32_16x16x32_bf16(qa[kd], kf, s[n], 0, 0, 0);
        }

      // ---- fixed-max softmax -> P in per-wave LDS ----
      bool okm[4];
      #pragma unroll
      for (int n = 0; n < 4; n++) okm[n] = (mk[cur][n * 16 + fc] != 0.f);

      const bool fullt = (kt * 64 + 63 <= q0w);   // wave-uniform: no causal edge
      if (fullt) {
        #pragma unroll
        for (int r = 0; r < 4; r++)
          #pragma unroll
          for (int n = 0; n < 4; n++) {
            float p = okm[n] ? exp2f(s[n][r] * SCALE_LOG2E) : 0.f;
            st_swz16(pw, g4 + r, (n * 16 + fc) * 2, (__bf16)p);
          }
      } else {
        #pragma unroll
        for (int r = 0; r < 4; r++) {
          const int qg = q0w + g4 + r;
          #pragma unroll
          for (int n = 0; n < 4; n++) {
            bool ok = okm[n] && (kt * 64 + n * 16 + fc <= qg);
            float p = ok ? exp2f(s[n][r] * SCALE_LOG2E) : 0.f;
            st_swz16(pw, g4 + r, (n * 16 + fc) * 2, (__bf16)p);
          }
        }
      }

      // ---- PV (+ row-sum l via ones-MFMA) ----
      #pragma unroll
      for (int kc = 0; kc < 2; kc++) {
        bf16x8 pf = ld_swz(pw, fc, kc * 64 + kg * 16);
        accl = __builtin_amdgcn_mfma_f32_16x16x32_bf16(pf, ones, accl, 0, 0, 0);
        #pragma unroll
        for (int n = 0; n < 4; n++) {
          bf16x8 vf = ld_swz(vs, n * 16 + fc, kc * 64 + kg * 16);
          acc[n] = __builtin_amdgcn_mfma_f32_16x16x32_bf16(pf, vf, acc[n], 0, 0, 0);
        }
      }
    }
    __builtin_amdgcn_s_barrier();   // all waves done reading cur before overwrite
  }

  #pragma unroll
  for (int r = 0; r < 4; r++) {
    float inv = accl[r] > 0.f ? 1.f / accl[r] : 0.f;
    __bf16* op = O + (tokbase + q0w + g4 + r) * HID_ + h * HD_;
    #pragma unroll
    for (int n = 0; n < 4; n++)
      op[n * 16 + fc] = (__bf16)(acc[n][r] * inv);
  }
}

// ---------------- state = K^T V via MFMA (needs Kt, Vt) ------------
// grid (32 bh, 16 sc), 256 thr = 4 waves. Tile: 128 tokens, full 64x64 out.
__global__ __launch_bounds__(256) void state_mfma(
    const __bf16* __restrict__ Kt, const __bf16* __restrict__ Vt,
    float* __restrict__ part)
{
  __shared__ __bf16 Kl[64 * 128];   // [d][s] swizzled, 256B rows
  __shared__ __bf16 Vl[64 * 128];   // [e][s] swizzled
  const int bh = blockIdx.x, sc = blockIdx.y;
  const int b = bh >> 4, h = bh & 15;
  const int t = threadIdx.x;
  const int w = t >> 6;
  const int lane = t & 63;
  const int fc = lane & 15;
  const int kg = lane >> 4;
  const size_t colbase = (size_t)b * S_ + sc * 128;
  const int rloc = lane >> 4;               // row within 4-row group
  const int cb = (lane & 15) * 16;          // dest byte col in 256B row

  #pragma unroll
  for (int c = 0; c < 4; c++) {
    int row = w * 16 + c * 4 + rloc;
    int scol = (cb ^ ((row & 7) << 4)) >> 1;   // pre-swizzled source col (shorts)
    gl16(&Kl[(w * 16 + c * 4) * 128], Kt + (size_t)(h * HD_ + row) * MTOK + colbase + scol);
    gl16(&Vl[(w * 16 + c * 4) * 128], Vt + (size_t)(h * HD_ + row) * MTOK + colbase + scol);
  }
  __syncthreads();

  f32x4 acc[4];
  #pragma unroll
  for (int n = 0; n < 4; n++) acc[n] = (f32x4)0.f;
  #pragma unroll
  for (int ks = 0; ks < 4; ks++) {
    bf16x8 af = ld_swz256(Kl, w * 16 + fc, ks * 64 + kg * 16);
    #pragma unroll
    for (int n = 0; n < 4; n++) {
      bf16x8 bfr = ld_swz256(Vl, n * 16 + fc, ks * 64 + kg * 16);
      acc[n] = __builtin_amdgcn_mfma_f32_16x16x32_bf16(af, bfr, acc[n], 0, 0, 0);
    }
  }

  float* dst = part + (((size_t)bh * 16 + sc) << 12);
  #pragma unroll
  for (int n = 0; n < 4; n++)
    #pragma unroll
    for (int r = 0; r < 4; r++)
      dst[(w * 16 + kg * 4 + r) * 64 + n * 16 + fc] = acc[n][r];
}

__global__ __launch_bounds__(256) void state_reduce(
    const float* __restrict__ part, float* __restrict__ out)
{
  int i = blockIdx.x * 256 + threadIdx.x;
  int bh = i >> 12, de = i & 4095;
  float s = 0.f;
  #pragma unroll
  for (int sc = 0; sc < 16; sc++) s += part[(((size_t)bh * 16 + sc) << 12) + de];
  out[i] = s;
}

// -------------------------------------------------------------------
extern "C" void kernel_launch(void* const* d_in, const int* in_sizes, int n_in,
                              void* d_out, int out_size, void* d_ws, size_t ws_size,
                              hipStream_t stream)
{
  const float* hs   = (const float*)d_in[0];
  const float* mask = (const float*)d_in[1];
  const float* Wq   = (const float*)d_in[2];
  const float* bq   = (const float*)d_in[3];
  const float* Wk   = (const float*)d_in[4];
  const float* bk   = (const float*)d_in[5];
  const float* Wv   = (const float*)d_in[6];
  const float* bv   = (const float*)d_in[7];
  const float* Wo   = (const float*)d_in[8];
  const float* bo   = (const float*)d_in[9];
  float* out = (float*)d_out;

  char* ws = (char*)d_ws;
  __bf16* Wqkvb = (__bf16*)(ws);                 // 6 MB; dead after gemm_qkv
  __bf16* Wob   = (__bf16*)(ws + (6u  << 20));   // 2 MB; dead after gemm_o
  __bf16* Xb    = (__bf16*)(ws + (8u  << 20));   // 8 MB; reused as Vt
  __bf16* QKV   = (__bf16*)(ws + (16u << 20));   // 24 MB [4096][3072]
  __bf16* Ob    = (__bf16*)(ws + (40u << 20));   // 8 MB
  float*  part  = (float*)(ws + (48u << 20));    // 8 MB

  cast_all<<<8192, 256, 0, stream>>>(hs, Wq, Wk, Wv, Wo, Xb, Wqkvb, Wob);

  gemm_qkv<<<dim3(LDQKV / 128, MTOK / 128), 256, 0, stream>>>(
      Xb, Wqkvb, bq, bk, bv, mask, QKV);

  // Xb dead -> reuse as V^T [HID][MTOK]
  __bf16* Vtg = Xb;
  transpose_bf16<<<dim3(MTOK / 64, HID_ / 64), 256, 0, stream>>>(QKV + 2048, LDQKV, Vtg);

  flash_mfma<<<dim3(B_ * NH_, S_ / 128), 512, 0, stream>>>(
      QKV, QKV + 1024, Vtg, mask, Ob);

  gemm_o<<<dim3(HID_ / 128, MTOK / 128), 256, 0, stream>>>(Ob, Wob, bo, out);

  // Wqkvb+Wob dead -> reuse as K^T [HID][MTOK] (8 MB)
  __bf16* Ktg = Wqkvb;
  transpose_bf16<<<dim3(MTOK / 64, HID_ / 64), 256, 0, stream>>>(QKV + 1024, LDQKV, Ktg);

  state_mfma<<<dim3(B_ * NH_, 16), 256, 0, stream>>>(Ktg, Vtg, part);
  state_reduce<<<512, 256, 0, stream>>>(part, out + (size_t)MTOK * HID_);
}